// Round 11
// baseline (129.811 us; speedup 1.0000x reference)
//
#include <hip/hip_runtime.h>

#define NUM_NODES 10000
#define NUM_EDGES 640000
#define D_FEAT 128

// Buckets of 20 nodes: 10000/20 = 500 exactly. 500 K2 blocks, 2/CU resident.
#define NPB 20
#define NB 500
#define K1_BLOCKS 256
#define EPB (NUM_EDGES / K1_BLOCKS)      // 2500 edges per block
// Cell (k,b): count ~ Poisson(2500*20/10000 = 5). CELL_CAP=16 words = 64 B =
// one line, block-private (XCD-safe). P(cell>16|lam=5) ~ 1.4e-5 -> ~2
// expected overflows total; they go to the per-block ovfcell line.
// LESSON (R4): global atomic binning = 195us. LESSON (R7): K1+K2 ~ 24-27us of
// dur~81-85; harness floor ~57us (43.8 fill + ~13 resets). LESSON (R8):
// memset removal + coalesced cell write = -3.4us. LESSONS (R8/R10): K2
// rebalance AND K2 interleaved-pair depth-4 gather both NULL -> K2 is not
// ILP-bound; K1/K2 split unknown.
//
// R11 = SPLIT MEASUREMENT: K2 launched 4x (idempotent: reads workspace,
// writes out). (dur11 - dur10)/3 = K2 + gap. Resolves which kernel owns
// the ~24us before any further edits.
#define CELL_CAP 16
#define MAXB 1664                        // bucket total: mean 1280 + 10 sigma

// x in bf16: one row = 128 bf16 = 256 B = 16 uint4.
#define XB_U4 (NUM_NODES * 16)           // 160000 uint4
#define CVT_PER_BLOCK (XB_U4 / K1_BLOCKS) // 625 uint4 per block

// ---------------------------------------------------------------------------
// Workspace (d_ws):
//   xb      [XB_U4]                uint4 -- x in bf16 (2.56 MB)
//   cnt     [K1_BLOCKS*NB]         u32   -- uncapped cursors (0.512 MB)
//   ovfcell [K1_BLOCKS*16]         u32   -- per-block overflow line (16 KB)
//   slots   [NB*K1_BLOCKS*CELL_CAP]u32   -- cell (k,b) at (k*256+b)*16 (8.19 MB)
// Total ~11.3 MB. No memset needed.
// ---------------------------------------------------------------------------

__device__ __forceinline__ unsigned bf16_rne(float f) {
    unsigned u = __float_as_uint(f);
    return (u + 0x7FFFu + ((u >> 16) & 1u)) >> 16;
}

__device__ __forceinline__ int bucket_of(int d) {
    // exact floor(d/20) for 0 <= d < 262144 (Granlund-Montgomery)
    return (int)(((unsigned)d * 104858u) >> 21);
}

// K1: fused f32->bf16 conversion + LDS-cell scatter + coalesced full-line
// cell write-out. BYTE-IDENTICAL to R10.
__global__ __launch_bounds__(1024) void scatter_cvt_kernel(
    const int* __restrict__ ei, const float4* __restrict__ x4,
    uint4* __restrict__ xb, unsigned* __restrict__ cnt,
    unsigned* __restrict__ ovfcell, uint4* __restrict__ slots4)
{
    __shared__ int cur[NB];
    __shared__ uint4 cellsv[NB * (CELL_CAP / 4)];   // 32 KB: [k][16 words]
    __shared__ unsigned s_ovf[16];
    __shared__ int ovfcur;

    int t = threadIdx.x, b = blockIdx.x;
    if (t < NB) cur[t] = 0;
    if (t < 16) s_ovf[t] = 0xFFFFFFFFu;             // sentinel: k-field 8191
    if (t == 0) ovfcur = 0;

    // hoisted edge loads: 2500 over 1024 threads = 2 rounds + tail
    int base = b * EPB;
    int s0 = ei[base + t];
    int d0 = ei[NUM_EDGES + base + t];
    int s1 = ei[base + t + 1024];                   // t+1024 <= 2047 < 2500
    int d1 = ei[NUM_EDGES + base + t + 1024];
    int s2 = 0, d2 = 0;
    bool has2 = (t + 2048) < EPB;                   // t < 452
    if (has2) {
        s2 = ei[base + t + 2048];
        d2 = ei[NUM_EDGES + base + t + 2048];
    }

    // fused conversion: 625 uint4 (= 5000 floats) per block
    if (t < CVT_PER_BLOCK) {
        int o = b * CVT_PER_BLOCK + t;
        float4 a = x4[2 * o];
        float4 c = x4[2 * o + 1];
        uint4 w;
        w.x = bf16_rne(a.x) | (bf16_rne(a.y) << 16);
        w.y = bf16_rne(a.z) | (bf16_rne(a.w) << 16);
        w.z = bf16_rne(c.x) | (bf16_rne(c.y) << 16);
        w.w = bf16_rne(c.z) | (bf16_rne(c.w) << 16);
        xb[o] = w;
    }
    __syncthreads();    // cur/s_ovf init done

    unsigned* cells = (unsigned*)cellsv;
    {
        int k = bucket_of(d0), m = d0 - k * NPB;
        int pos = atomicAdd(&cur[k], 1);
        if (pos < CELL_CAP)
            cells[k * CELL_CAP + pos] = ((unsigned)m << 16) | (unsigned)s0;
        else {
            int o = atomicAdd(&ovfcur, 1);
            if (o < 16) s_ovf[o] = ((unsigned)k << 19) |
                                   ((unsigned)m << 14) | (unsigned)s0;
        }
    }
    {
        int k = bucket_of(d1), m = d1 - k * NPB;
        int pos = atomicAdd(&cur[k], 1);
        if (pos < CELL_CAP)
            cells[k * CELL_CAP + pos] = ((unsigned)m << 16) | (unsigned)s1;
        else {
            int o = atomicAdd(&ovfcur, 1);
            if (o < 16) s_ovf[o] = ((unsigned)k << 19) |
                                   ((unsigned)m << 14) | (unsigned)s1;
        }
    }
    if (has2) {
        int k = bucket_of(d2), m = d2 - k * NPB;
        int pos = atomicAdd(&cur[k], 1);
        if (pos < CELL_CAP)
            cells[k * CELL_CAP + pos] = ((unsigned)m << 16) | (unsigned)s2;
        else {
            int o = atomicAdd(&ovfcur, 1);
            if (o < 16) s_ovf[o] = ((unsigned)k << 19) |
                                   ((unsigned)m << 14) | (unsigned)s2;
        }
    }
    __syncthreads();

    // coalesced cell write-out: 4 consecutive lanes emit one full 64 B line
    for (int idx = t; idx < NB * (CELL_CAP / 4); idx += 1024) {
        int k = idx >> 2, j = idx & 3;
        slots4[((unsigned)k * K1_BLOCKS + (unsigned)b) * (CELL_CAP / 4) + j] =
            cellsv[idx];
    }
    // uncapped cursor row (block-private lines) + sentinel-padded ovf line
    if (t < NB) cnt[b * NB + t] = (unsigned)cur[t];
    if (t < 16) ovfcell[b * 16 + t] = s_ovf[t];
}

__device__ __forceinline__ void acc8(float* a, uint4 w) {
    a[0] += __uint_as_float(w.x << 16);
    a[1] += __uint_as_float(w.x & 0xFFFF0000u);
    a[2] += __uint_as_float(w.y << 16);
    a[3] += __uint_as_float(w.y & 0xFFFF0000u);
    a[4] += __uint_as_float(w.z << 16);
    a[5] += __uint_as_float(w.z & 0xFFFF0000u);
    a[6] += __uint_as_float(w.w << 16);
    a[7] += __uint_as_float(w.w & 0xFFFF0000u);
}

__device__ __forceinline__ void reduce_write(float* a, int node, int q, int sub,
                                             float4* __restrict__ out4) {
    #pragma unroll
    for (int r = 0; r < 8; ++r) {
        a[r] += __shfl_down(a[r], 32);
        a[r] += __shfl_down(a[r], 16);
    }
    if (q == 0) {
        unsigned o = (unsigned)node * 32u + (unsigned)sub * 2u;
        out4[o]     = make_float4(a[0], a[1], a[2], a[3]);
        out4[o + 1] = make_float4(a[4], a[5], a[6], a[7]);
    }
}

// K2: per-bucket sort + gather. BYTE-IDENTICAL to R10. Idempotent.
__global__ __launch_bounds__(640, 5) void sort_gather_kernel(
    const uint4* __restrict__ xb,            // [NUM_NODES*16] bf16 rows
    const unsigned* __restrict__ cnt,        // [K1_BLOCKS*NB] uncapped
    const uint4* __restrict__ slots4,        // cells, 4 uint4 each
    const unsigned* __restrict__ ovfcell,    // [K1_BLOCKS*16]
    float4* __restrict__ out4)               // [NUM_NODES*32]
{
    __shared__ int s_cnt[K1_BLOCKS];
    __shared__ unsigned s_src[MAXB];
    __shared__ int h[NPB];
    __shared__ int off20[NPB];
    __shared__ int cur20[NPB];

    int k = blockIdx.x;
    int t = threadIdx.x;

    if (t < NPB) h[t] = 0;
    if (t < K1_BLOCKS) s_cnt[t] = (int)cnt[t * NB + k];   // strided, L2-hot
    __syncthreads();

    // bucket's 256 cells = 1024 uint4, read in 2 coalesced rounds
    const uint4* sb = slots4 + (unsigned)k * (K1_BLOCKS * CELL_CAP / 4);
    uint4 w40, w41 = make_uint4(0u, 0u, 0u, 0u);
    int vc0, vc1 = 0;
    {
        int c = t >> 2, su = t & 3;
        w40 = sb[t];
        int v = min(s_cnt[c], CELL_CAP) - su * 4;
        vc0 = max(0, min(4, v));
    }
    if (t < 384) {                                        // t+640 < 1024
        int idx = t + 640;
        int c = idx >> 2, su = idx & 3;
        w41 = sb[idx];
        int v = min(s_cnt[c], CELL_CAP) - su * 4;
        vc1 = max(0, min(4, v));
    }
    if (vc0 > 0) atomicAdd(&h[w40.x >> 16], 1);
    if (vc0 > 1) atomicAdd(&h[w40.y >> 16], 1);
    if (vc0 > 2) atomicAdd(&h[w40.z >> 16], 1);
    if (vc0 > 3) atomicAdd(&h[w40.w >> 16], 1);
    if (vc1 > 0) atomicAdd(&h[w41.x >> 16], 1);
    if (vc1 > 1) atomicAdd(&h[w41.y >> 16], 1);
    if (vc1 > 2) atomicAdd(&h[w41.z >> 16], 1);
    if (vc1 > 3) atomicAdd(&h[w41.w >> 16], 1);
    // rare overflow path: cnt>CAP flags block t's ovfcell line
    if (t < K1_BLOCKS && s_cnt[t] > CELL_CAP) {
        for (int i = 0; i < 16; ++i) {
            unsigned e = ovfcell[t * 16 + i];
            if ((int)(e >> 19) == k) atomicAdd(&h[(e >> 14) & 31u], 1);
        }
    }
    __syncthreads();

    // 32-lane shfl prefix scan over 20 counters (wave 0)
    if (t < 32) {
        int val = (t < NPB) ? h[t] : 0;
        int s = val;
        #pragma unroll
        for (int d = 1; d < 32; d <<= 1) {
            int u = __shfl_up(s, d, 32);
            if (t >= d) s += u;
        }
        if (t < NPB) { off20[t] = s - val; cur20[t] = s - val; }
    }
    __syncthreads();

    // compact into s_src grouped by node
    if (vc0 > 0) { int p = atomicAdd(&cur20[w40.x >> 16], 1); if (p < MAXB) s_src[p] = w40.x & 0xFFFFu; }
    if (vc0 > 1) { int p = atomicAdd(&cur20[w40.y >> 16], 1); if (p < MAXB) s_src[p] = w40.y & 0xFFFFu; }
    if (vc0 > 2) { int p = atomicAdd(&cur20[w40.z >> 16], 1); if (p < MAXB) s_src[p] = w40.z & 0xFFFFu; }
    if (vc0 > 3) { int p = atomicAdd(&cur20[w40.w >> 16], 1); if (p < MAXB) s_src[p] = w40.w & 0xFFFFu; }
    if (vc1 > 0) { int p = atomicAdd(&cur20[w41.x >> 16], 1); if (p < MAXB) s_src[p] = w41.x & 0xFFFFu; }
    if (vc1 > 1) { int p = atomicAdd(&cur20[w41.y >> 16], 1); if (p < MAXB) s_src[p] = w41.y & 0xFFFFu; }
    if (vc1 > 2) { int p = atomicAdd(&cur20[w41.z >> 16], 1); if (p < MAXB) s_src[p] = w41.z & 0xFFFFu; }
    if (vc1 > 3) { int p = atomicAdd(&cur20[w41.w >> 16], 1); if (p < MAXB) s_src[p] = w41.w & 0xFFFFu; }
    if (t < K1_BLOCKS && s_cnt[t] > CELL_CAP) {
        for (int i = 0; i < 16; ++i) {
            unsigned e = ovfcell[t * 16 + i];
            if ((int)(e >> 19) == k) {
                int p = atomicAdd(&cur20[(e >> 14) & 31u], 1);
                if (p < MAXB) s_src[p] = e & 0x3FFFu;
            }
        }
    }
    __syncthreads();

    int wave = t >> 6;          // 0..9
    int lane = t & 63;
    int q    = lane >> 4;       // which edge of the quad
    int sub  = lane & 15;       // 16 B chunk (8 bf16) within the row

    int mA = wave;              // interleaved node pair for this wave
    int mB = wave + 10;
    int begA = off20[mA], ecA = h[mA];
    int begB = off20[mB], ecB = h[mB];
    int lastA = ecA > 0 ? ecA - 1 : 0;
    int lastB = ecB > 0 ? ecB - 1 : 0;

    float aA[8] = {0.f, 0.f, 0.f, 0.f, 0.f, 0.f, 0.f, 0.f};
    float aB[8] = {0.f, 0.f, 0.f, 0.f, 0.f, 0.f, 0.f, 0.f};

    // depth-4 pipeline: groups j for BOTH nodes in regs while j+4 prefetch
    bool vA = q < ecA, vB = q < ecB;
    unsigned iA = (unsigned)min(begA + min(q, lastA), MAXB - 1);
    unsigned iB = (unsigned)min(begB + min(q, lastB), MAXB - 1);
    uint4 wA = xb[(s_src[iA] & 0xFFFFu) * 16u + (unsigned)sub];
    uint4 wB = xb[(s_src[iB] & 0xFFFFu) * 16u + (unsigned)sub];

    int jmax = max(ecA, ecB);
    for (int j = 0; j < jmax; j += 4) {
        int jn = j + 4;
        unsigned iA2 = (unsigned)min(begA + min(jn + q, lastA), MAXB - 1);
        unsigned iB2 = (unsigned)min(begB + min(jn + q, lastB), MAXB - 1);
        uint4 wA2 = xb[(s_src[iA2] & 0xFFFFu) * 16u + (unsigned)sub];
        uint4 wB2 = xb[(s_src[iB2] & 0xFFFFu) * 16u + (unsigned)sub];
        bool vA2 = (jn + q) < ecA;
        bool vB2 = (jn + q) < ecB;
        if (vA) acc8(aA, wA);
        if (vB) acc8(aB, wB);
        wA = wA2; vA = vA2;
        wB = wB2; vB = vB2;
    }

    reduce_write(aA, k * NPB + mA, q, sub, out4);
    reduce_write(aB, k * NPB + mB, q, sub, out4);
}

extern "C" void kernel_launch(void* const* d_in, const int* in_sizes, int n_in,
                              void* d_out, int out_size, void* d_ws, size_t ws_size,
                              hipStream_t stream) {
    const float* x   = (const float*)d_in[0];   // [10000, 128] f32
    const int*   ei  = (const int*)d_in[1];     // [2, 640000] int32
    float*       out = (float*)d_out;           // [10000, 128] f32

    uint4*    xb      = (uint4*)d_ws;                        // 2.56 MB
    unsigned* cnt     = (unsigned*)(xb + XB_U4);             // 0.512 MB
    unsigned* ovfcell = cnt + K1_BLOCKS * NB;                // 16 KB
    uint4*    slots4  = (uint4*)(ovfcell + K1_BLOCKS * 16);  // 8.19 MB

    // K1: convert x -> bf16 + LDS-cell scatter + coalesced cell write-out
    scatter_cvt_kernel<<<K1_BLOCKS, 1024, 0, stream>>>(
        ei, (const float4*)x, xb, cnt, ovfcell, slots4);

    // K2 x4: MEASUREMENT. Idempotent (pure read of workspace -> write out).
    // (dur11 - dur10)/3 = K2 + launch gap. Final launch produces the
    // graded output (identical every time).
    sort_gather_kernel<<<NB, 640, 0, stream>>>(
        xb, cnt, (const uint4*)slots4, ovfcell, (float4*)out);
    sort_gather_kernel<<<NB, 640, 0, stream>>>(
        xb, cnt, (const uint4*)slots4, ovfcell, (float4*)out);
    sort_gather_kernel<<<NB, 640, 0, stream>>>(
        xb, cnt, (const uint4*)slots4, ovfcell, (float4*)out);
    sort_gather_kernel<<<NB, 640, 0, stream>>>(
        xb, cnt, (const uint4*)slots4, ovfcell, (float4*)out);
}

// Round 12
// 85.385 us; speedup vs baseline: 1.5203x; 1.5203x over previous
//
#include <hip/hip_runtime.h>

#define NUM_NODES 10000
#define NUM_EDGES 640000
#define D_FEAT 128

// Buckets of 20 nodes: 10000/20 = 500 exactly.
#define NPB 20
#define NB 500
#define K1_BLOCKS 256
#define EPB (NUM_EDGES / K1_BLOCKS)      // 2500 edges per block
// Cell (k,b): Poisson(5); CELL_CAP=16 words = one line, block-private.
// LESSON (R4): global atomic binning = 195us. LESSON (R7/R11): floor ~57us,
// K1 ~8us, K2 ~16us (split-measured). LESSONS (R8/R10): gather ILP edits
// null -> K2's overhead is the sort/gather coupling (LDS-atomic sort through
// shared DS pipe at 2 blocks/CU, 10-wave barrier convoys). R12: split K2
// into sort-only (K2a) + barrier-free max-TLP gather (K2b).
#define CELL_CAP 16
#define MAXB 1664                        // bucket seg: 6656 B = 104 lines
#define NIW 32                           // nodeinfo words/bucket (128 B)

// x in bf16: one row = 128 bf16 = 256 B = 16 uint4.
#define XB_U4 (NUM_NODES * 16)           // 160000 uint4
#define CVT_PER_BLOCK (XB_U4 / K1_BLOCKS) // 625 uint4 per block

// ---------------------------------------------------------------------------
// Workspace (d_ws):
//   xb       [XB_U4]                uint4 -- x in bf16 (2.56 MB)
//   cnt      [K1_BLOCKS*NB]         u32   -- uncapped cursors (0.512 MB)
//   ovfcell  [K1_BLOCKS*16]         u32   -- per-block overflow line (16 KB)
//   slots    [NB*K1_BLOCKS*CELL_CAP]u32   -- cells (8.19 MB)
//   seg      [NB*MAXB]              u32   -- compacted per-bucket srcs (3.33 MB)
//   nodeinfo [NB*NIW]               u32   -- (beg<<16|cnt) per node (64 KB)
// Total ~14.7 MB. No memset needed.
// ---------------------------------------------------------------------------

__device__ __forceinline__ unsigned bf16_rne(float f) {
    unsigned u = __float_as_uint(f);
    return (u + 0x7FFFu + ((u >> 16) & 1u)) >> 16;
}

__device__ __forceinline__ int div20(int d) {
    // exact floor(d/20) for 0 <= d < 262144 (Granlund-Montgomery)
    return (int)(((unsigned)d * 104858u) >> 21);
}

// K1: fused f32->bf16 conversion + LDS-cell scatter + coalesced full-line
// cell write-out. BYTE-IDENTICAL to R10.
__global__ __launch_bounds__(1024) void scatter_cvt_kernel(
    const int* __restrict__ ei, const float4* __restrict__ x4,
    uint4* __restrict__ xb, unsigned* __restrict__ cnt,
    unsigned* __restrict__ ovfcell, uint4* __restrict__ slots4)
{
    __shared__ int cur[NB];
    __shared__ uint4 cellsv[NB * (CELL_CAP / 4)];   // 32 KB
    __shared__ unsigned s_ovf[16];
    __shared__ int ovfcur;

    int t = threadIdx.x, b = blockIdx.x;
    if (t < NB) cur[t] = 0;
    if (t < 16) s_ovf[t] = 0xFFFFFFFFu;             // sentinel
    if (t == 0) ovfcur = 0;

    int base = b * EPB;
    int s0 = ei[base + t];
    int d0 = ei[NUM_EDGES + base + t];
    int s1 = ei[base + t + 1024];
    int d1 = ei[NUM_EDGES + base + t + 1024];
    int s2 = 0, d2 = 0;
    bool has2 = (t + 2048) < EPB;
    if (has2) {
        s2 = ei[base + t + 2048];
        d2 = ei[NUM_EDGES + base + t + 2048];
    }

    if (t < CVT_PER_BLOCK) {
        int o = b * CVT_PER_BLOCK + t;
        float4 a = x4[2 * o];
        float4 c = x4[2 * o + 1];
        uint4 w;
        w.x = bf16_rne(a.x) | (bf16_rne(a.y) << 16);
        w.y = bf16_rne(a.z) | (bf16_rne(a.w) << 16);
        w.z = bf16_rne(c.x) | (bf16_rne(c.y) << 16);
        w.w = bf16_rne(c.z) | (bf16_rne(c.w) << 16);
        xb[o] = w;
    }
    __syncthreads();

    unsigned* cells = (unsigned*)cellsv;
    {
        int k = div20(d0), m = d0 - k * NPB;
        int pos = atomicAdd(&cur[k], 1);
        if (pos < CELL_CAP)
            cells[k * CELL_CAP + pos] = ((unsigned)m << 16) | (unsigned)s0;
        else {
            int o = atomicAdd(&ovfcur, 1);
            if (o < 16) s_ovf[o] = ((unsigned)k << 19) |
                                   ((unsigned)m << 14) | (unsigned)s0;
        }
    }
    {
        int k = div20(d1), m = d1 - k * NPB;
        int pos = atomicAdd(&cur[k], 1);
        if (pos < CELL_CAP)
            cells[k * CELL_CAP + pos] = ((unsigned)m << 16) | (unsigned)s1;
        else {
            int o = atomicAdd(&ovfcur, 1);
            if (o < 16) s_ovf[o] = ((unsigned)k << 19) |
                                   ((unsigned)m << 14) | (unsigned)s1;
        }
    }
    if (has2) {
        int k = div20(d2), m = d2 - k * NPB;
        int pos = atomicAdd(&cur[k], 1);
        if (pos < CELL_CAP)
            cells[k * CELL_CAP + pos] = ((unsigned)m << 16) | (unsigned)s2;
        else {
            int o = atomicAdd(&ovfcur, 1);
            if (o < 16) s_ovf[o] = ((unsigned)k << 19) |
                                   ((unsigned)m << 14) | (unsigned)s2;
        }
    }
    __syncthreads();

    for (int idx = t; idx < NB * (CELL_CAP / 4); idx += 1024) {
        int k = idx >> 2, j = idx & 3;
        slots4[((unsigned)k * K1_BLOCKS + (unsigned)b) * (CELL_CAP / 4) + j] =
            cellsv[idx];
    }
    if (t < NB) cnt[b * NB + t] = (unsigned)cur[t];
    if (t < 16) ovfcell[b * 16 + t] = s_ovf[t];
}

// K2a: SORT ONLY -- hist/scan/compact (as R10) then write compacted srcs +
// per-node (beg,cnt) to global. No gather: short, low-VGPR, exits fast.
__global__ __launch_bounds__(640, 5) void sort_kernel(
    const unsigned* __restrict__ cnt,        // [K1_BLOCKS*NB] uncapped
    const uint4* __restrict__ slots4,        // cells, 4 uint4 each
    const unsigned* __restrict__ ovfcell,    // [K1_BLOCKS*16]
    unsigned* __restrict__ seg,              // [NB*MAXB]
    unsigned* __restrict__ nodeinfo)         // [NB*NIW]
{
    __shared__ int s_cnt[K1_BLOCKS];
    __shared__ unsigned s_src[MAXB];
    __shared__ int h[NPB];
    __shared__ int off20[NPB];
    __shared__ int cur20[NPB];

    int k = blockIdx.x;
    int t = threadIdx.x;

    if (t < NPB) h[t] = 0;
    if (t < K1_BLOCKS) s_cnt[t] = (int)cnt[t * NB + k];
    __syncthreads();

    const uint4* sb = slots4 + (unsigned)k * (K1_BLOCKS * CELL_CAP / 4);
    uint4 w40, w41 = make_uint4(0u, 0u, 0u, 0u);
    int vc0, vc1 = 0;
    {
        int c = t >> 2, su = t & 3;
        w40 = sb[t];
        int v = min(s_cnt[c], CELL_CAP) - su * 4;
        vc0 = max(0, min(4, v));
    }
    if (t < 384) {
        int idx = t + 640;
        int c = idx >> 2, su = idx & 3;
        w41 = sb[idx];
        int v = min(s_cnt[c], CELL_CAP) - su * 4;
        vc1 = max(0, min(4, v));
    }
    if (vc0 > 0) atomicAdd(&h[w40.x >> 16], 1);
    if (vc0 > 1) atomicAdd(&h[w40.y >> 16], 1);
    if (vc0 > 2) atomicAdd(&h[w40.z >> 16], 1);
    if (vc0 > 3) atomicAdd(&h[w40.w >> 16], 1);
    if (vc1 > 0) atomicAdd(&h[w41.x >> 16], 1);
    if (vc1 > 1) atomicAdd(&h[w41.y >> 16], 1);
    if (vc1 > 2) atomicAdd(&h[w41.z >> 16], 1);
    if (vc1 > 3) atomicAdd(&h[w41.w >> 16], 1);
    if (t < K1_BLOCKS && s_cnt[t] > CELL_CAP) {
        for (int i = 0; i < 16; ++i) {
            unsigned e = ovfcell[t * 16 + i];
            if ((int)(e >> 19) == k) atomicAdd(&h[(e >> 14) & 31u], 1);
        }
    }
    __syncthreads();

    if (t < 32) {
        int val = (t < NPB) ? h[t] : 0;
        int s = val;
        #pragma unroll
        for (int d = 1; d < 32; d <<= 1) {
            int u = __shfl_up(s, d, 32);
            if (t >= d) s += u;
        }
        if (t < NPB) { off20[t] = s - val; cur20[t] = s - val; }
    }
    __syncthreads();

    if (vc0 > 0) { int p = atomicAdd(&cur20[w40.x >> 16], 1); if (p < MAXB) s_src[p] = w40.x & 0xFFFFu; }
    if (vc0 > 1) { int p = atomicAdd(&cur20[w40.y >> 16], 1); if (p < MAXB) s_src[p] = w40.y & 0xFFFFu; }
    if (vc0 > 2) { int p = atomicAdd(&cur20[w40.z >> 16], 1); if (p < MAXB) s_src[p] = w40.z & 0xFFFFu; }
    if (vc0 > 3) { int p = atomicAdd(&cur20[w40.w >> 16], 1); if (p < MAXB) s_src[p] = w40.w & 0xFFFFu; }
    if (vc1 > 0) { int p = atomicAdd(&cur20[w41.x >> 16], 1); if (p < MAXB) s_src[p] = w41.x & 0xFFFFu; }
    if (vc1 > 1) { int p = atomicAdd(&cur20[w41.y >> 16], 1); if (p < MAXB) s_src[p] = w41.y & 0xFFFFu; }
    if (vc1 > 2) { int p = atomicAdd(&cur20[w41.z >> 16], 1); if (p < MAXB) s_src[p] = w41.z & 0xFFFFu; }
    if (vc1 > 3) { int p = atomicAdd(&cur20[w41.w >> 16], 1); if (p < MAXB) s_src[p] = w41.w & 0xFFFFu; }
    if (t < K1_BLOCKS && s_cnt[t] > CELL_CAP) {
        for (int i = 0; i < 16; ++i) {
            unsigned e = ovfcell[t * 16 + i];
            if ((int)(e >> 19) == k) {
                int p = atomicAdd(&cur20[(e >> 14) & 31u], 1);
                if (p < MAXB) s_src[p] = e & 0x3FFFu;
            }
        }
    }
    __syncthreads();

    // coalesced seg write (104 full lines max, single-writer per bucket)
    int ntot = min(off20[NPB - 1] + h[NPB - 1], MAXB);
    for (int i = t; i < ntot; i += 640)
        seg[(unsigned)k * MAXB + (unsigned)i] = s_src[i];
    // per-node (beg,cnt), 128 B line-aligned per bucket, single-writer
    if (t < NPB)
        nodeinfo[k * NIW + t] =
            ((unsigned)off20[t] << 16) | (unsigned)min(h[t], 0xFFFF);
}

__device__ __forceinline__ void acc8(float* a, uint4 w) {
    a[0] += __uint_as_float(w.x << 16);
    a[1] += __uint_as_float(w.x & 0xFFFF0000u);
    a[2] += __uint_as_float(w.y << 16);
    a[3] += __uint_as_float(w.y & 0xFFFF0000u);
    a[4] += __uint_as_float(w.z << 16);
    a[5] += __uint_as_float(w.z & 0xFFFF0000u);
    a[6] += __uint_as_float(w.w << 16);
    a[7] += __uint_as_float(w.w & 0xFFFF0000u);
}

// K2b: PURE GATHER. 2500 blocks x 256 thr, one node per wave (10000 waves ~
// 9.8/SIMD offered), no barriers, no LDS, ~35 VGPR. src prefetched 2 trips
// ahead, row 1 trip ahead -> breaks the src->row serial chain; TLP does the
// rest.
__global__ __launch_bounds__(256) void gather_kernel(
    const uint4* __restrict__ xb,            // [NUM_NODES*16] bf16 rows
    const unsigned* __restrict__ seg,        // [NB*MAXB] srcs
    const unsigned* __restrict__ nodeinfo,   // [NB*NIW]
    float4* __restrict__ out4)               // [NUM_NODES*32]
{
    int wave = threadIdx.x >> 6;
    int lane = threadIdx.x & 63;
    int n = blockIdx.x * 4 + wave;           // 2500*4 = 10000 exact
    int k = div20(n), m = n - k * NPB;

    unsigned info = nodeinfo[k * NIW + m];   // broadcast load
    int beg = (int)(info >> 16);
    int ec  = (int)(info & 0xFFFFu);
    int last = ec > 0 ? ec - 1 : 0;

    const unsigned* sl = seg + (unsigned)k * MAXB;
    int q   = lane >> 4;                     // edge of the quad
    int sub = lane & 15;                     // 16 B chunk within the row

    float a[8] = {0.f, 0.f, 0.f, 0.f, 0.f, 0.f, 0.f, 0.f};

    // idx(x) clamped to the node's list and the segment
    unsigned i0 = (unsigned)min(beg + min(0 + q, last), MAXB - 1);
    unsigned i4 = (unsigned)min(beg + min(4 + q, last), MAXB - 1);
    unsigned sA = sl[i0];                    // src for j=0
    unsigned sB = sl[i4];                    // src for j=4 (1 trip lead)
    uint4 r = xb[(sA & 0xFFFFu) * 16u + (unsigned)sub];   // row j=0
    bool v = q < ec;

    for (int j = 0; j < ec; j += 4) {
        unsigned ic = (unsigned)min(beg + min(j + 8 + q, last), MAXB - 1);
        unsigned sC = sl[ic];                            // src j+8 (2-trip lead)
        uint4 r1 = xb[(sB & 0xFFFFu) * 16u + (unsigned)sub]; // row j+4
        bool v1 = (j + 4 + q) < ec;
        if (v) acc8(a, r);
        r = r1; v = v1; sB = sC;
    }

    #pragma unroll
    for (int rr = 0; rr < 8; ++rr) {
        a[rr] += __shfl_down(a[rr], 32);
        a[rr] += __shfl_down(a[rr], 16);
    }
    if (q == 0) {
        unsigned o = (unsigned)n * 32u + (unsigned)sub * 2u;
        out4[o]     = make_float4(a[0], a[1], a[2], a[3]);
        out4[o + 1] = make_float4(a[4], a[5], a[6], a[7]);
    }
}

extern "C" void kernel_launch(void* const* d_in, const int* in_sizes, int n_in,
                              void* d_out, int out_size, void* d_ws, size_t ws_size,
                              hipStream_t stream) {
    const float* x   = (const float*)d_in[0];   // [10000, 128] f32
    const int*   ei  = (const int*)d_in[1];     // [2, 640000] int32
    float*       out = (float*)d_out;           // [10000, 128] f32

    uint4*    xb       = (uint4*)d_ws;                           // 2.56 MB
    unsigned* cnt      = (unsigned*)(xb + XB_U4);                // 0.512 MB
    unsigned* ovfcell  = cnt + K1_BLOCKS * NB;                   // 16 KB
    uint4*    slots4   = (uint4*)(ovfcell + K1_BLOCKS * 16);     // 8.19 MB
    unsigned* seg      = (unsigned*)(slots4 +
                         (size_t)NB * K1_BLOCKS * (CELL_CAP / 4)); // 3.33 MB
    unsigned* nodeinfo = seg + (size_t)NB * MAXB;                // 64 KB

    // K1: convert x -> bf16 + LDS-cell scatter + coalesced cell write-out
    scatter_cvt_kernel<<<K1_BLOCKS, 1024, 0, stream>>>(
        ei, (const float4*)x, xb, cnt, ovfcell, slots4);

    // K2a: sort only (hist/scan/compact -> seg + nodeinfo)
    sort_kernel<<<NB, 640, 0, stream>>>(
        cnt, (const uint4*)slots4, ovfcell, seg, nodeinfo);

    // K2b: barrier-free max-TLP gather
    gather_kernel<<<NUM_NODES / 4, 256, 0, stream>>>(
        xb, seg, nodeinfo, (float4*)out);
}

// Round 13
// 81.592 us; speedup vs baseline: 1.5910x; 1.0465x over previous
//
#include <hip/hip_runtime.h>

#define NUM_NODES 10000
#define NUM_EDGES 640000
#define D_FEAT 128

// Buckets of 20 nodes: 10000/20 = 500 exactly.
#define NPB 20
#define NB 500
#define K1_BLOCKS 256
#define EPB (NUM_EDGES / K1_BLOCKS)      // 2500 edges per block
// Cell (k,b): Poisson(5); CELL_CAP=16 words = one 64B line, block-private.
// R13: SENTINEL cells (invalid word = 0xFFFFFFFF; valid iff m-field < 20)
// -> the cnt array, its staging, and all validity clamps are DELETED.
// Overflow (P ~ 1.4e-5/cell, ~2 expected grid-wide) goes to the per-block
// self-resetting ovfcell line; count in word 15 gates a never-taken slow path.
// ZERO-ROW padding: xb row 10000 is all zeros; s_src prefilled with it and
// node ranges padded -> gather loop has no masks/clamps at all.
// LESSONS: R4 global-atomic binning = 195us. R7/R11: floor ~57us, K1 ~8,
// K2 ~16. R8/R10/R12: gather ILP, balance, and sort/gather split all null
// or negative -> K2 is distributed overhead; delete phases, don't tune them.
#define CELL_CAP 16
#define MAXB 1792                        // Sum of padded ranges: <=1640+140
#define INV 0xFFFFFFFFu
#define ZROW 10000u                      // zero row index in xb

// x in bf16: one row = 128 bf16 = 256 B = 16 uint4. +16 for the zero row.
#define XB_U4 (NUM_NODES * 16 + 16)
#define CVT_PER_BLOCK (NUM_NODES * 16 / K1_BLOCKS)  // 625 uint4 per block

// ---------------------------------------------------------------------------
// Workspace (d_ws):
//   xb      [XB_U4]                uint4 -- x in bf16 + zero row (2.56 MB)
//   ovfcell [K1_BLOCKS*16]         u32   -- entries[0..14] + count[15] (16 KB)
//   slots   [NB*K1_BLOCKS*CELL_CAP]u32   -- sentinel cells (8.19 MB)
// Total ~10.8 MB. No memset, no cnt array.
// ---------------------------------------------------------------------------

__device__ __forceinline__ unsigned bf16_rne(float f) {
    unsigned u = __float_as_uint(f);
    return (u + 0x7FFFu + ((u >> 16) & 1u)) >> 16;
}

__device__ __forceinline__ int div20(int d) {
    // exact floor(d/20) for 0 <= d < 262144 (Granlund-Montgomery)
    return (int)(((unsigned)d * 104858u) >> 21);
}

// K1: fused f32->bf16 conversion + LDS-cell scatter (sentinel-prefilled) +
// coalesced full-line cell write-out. No cnt output.
__global__ __launch_bounds__(1024) void scatter_cvt_kernel(
    const int* __restrict__ ei, const float4* __restrict__ x4,
    uint4* __restrict__ xb, unsigned* __restrict__ ovfcell,
    uint4* __restrict__ slots4)
{
    __shared__ int cur[NB];
    __shared__ uint4 cellsv[NB * (CELL_CAP / 4)];   // 32 KB
    __shared__ unsigned s_ovf[15];
    __shared__ int ovfcur;

    int t = threadIdx.x, b = blockIdx.x;
    if (t < NB) cur[t] = 0;
    if (t < 15) s_ovf[t] = 0;
    if (t == 0) ovfcur = 0;
    // sentinel prefill: 2000 uint4 over 1024 threads
    uint4 iv = make_uint4(INV, INV, INV, INV);
    if (t < 1000) { cellsv[t] = iv; cellsv[t + 1000] = iv; }

    // hoisted edge loads: 2500 over 1024 threads = 2 rounds + tail
    int base = b * EPB;
    int s0 = ei[base + t];
    int d0 = ei[NUM_EDGES + base + t];
    int s1 = ei[base + t + 1024];                   // t+1024 <= 2047 < 2500
    int d1 = ei[NUM_EDGES + base + t + 1024];
    int s2 = 0, d2 = 0;
    bool has2 = (t + 2048) < EPB;                   // t < 452
    if (has2) {
        s2 = ei[base + t + 2048];
        d2 = ei[NUM_EDGES + base + t + 2048];
    }

    // fused conversion: 625 uint4 (= 5000 floats) per block
    if (t < CVT_PER_BLOCK) {
        int o = b * CVT_PER_BLOCK + t;
        float4 a = x4[2 * o];
        float4 c = x4[2 * o + 1];
        uint4 w;
        w.x = bf16_rne(a.x) | (bf16_rne(a.y) << 16);
        w.y = bf16_rne(a.z) | (bf16_rne(a.w) << 16);
        w.z = bf16_rne(c.x) | (bf16_rne(c.y) << 16);
        w.w = bf16_rne(c.z) | (bf16_rne(c.w) << 16);
        xb[o] = w;
    }
    // zero row (single-writer: block 0 only; its own cache line)
    if (b == 0 && t < 16)
        xb[NUM_NODES * 16 + t] = make_uint4(0u, 0u, 0u, 0u);
    __syncthreads();    // cur/cells/s_ovf init done

    unsigned* cells = (unsigned*)cellsv;
    {
        int k = div20(d0), m = d0 - k * NPB;
        int pos = atomicAdd(&cur[k], 1);
        if (pos < CELL_CAP)
            cells[k * CELL_CAP + pos] = ((unsigned)m << 16) | (unsigned)s0;
        else {
            int o = atomicAdd(&ovfcur, 1);
            if (o < 15) s_ovf[o] = ((unsigned)k << 19) |
                                   ((unsigned)m << 14) | (unsigned)s0;
        }
    }
    {
        int k = div20(d1), m = d1 - k * NPB;
        int pos = atomicAdd(&cur[k], 1);
        if (pos < CELL_CAP)
            cells[k * CELL_CAP + pos] = ((unsigned)m << 16) | (unsigned)s1;
        else {
            int o = atomicAdd(&ovfcur, 1);
            if (o < 15) s_ovf[o] = ((unsigned)k << 19) |
                                   ((unsigned)m << 14) | (unsigned)s1;
        }
    }
    if (has2) {
        int k = div20(d2), m = d2 - k * NPB;
        int pos = atomicAdd(&cur[k], 1);
        if (pos < CELL_CAP)
            cells[k * CELL_CAP + pos] = ((unsigned)m << 16) | (unsigned)s2;
        else {
            int o = atomicAdd(&ovfcur, 1);
            if (o < 15) s_ovf[o] = ((unsigned)k << 19) |
                                   ((unsigned)m << 14) | (unsigned)s2;
        }
    }
    __syncthreads();

    // coalesced cell write-out: full 64 B lines, block-private
    for (int idx = t; idx < NB * (CELL_CAP / 4); idx += 1024)
        slots4[((unsigned)(idx >> 2) * K1_BLOCKS + (unsigned)b) *
               (CELL_CAP / 4) + (unsigned)(idx & 3)] = cellsv[idx];
    // self-resetting overflow line: entries + count word
    if (t < 15) ovfcell[b * 16 + t] = s_ovf[t];
    if (t == 15) ovfcell[b * 16 + 15] = (unsigned)min(ovfcur, 15);
}

__device__ __forceinline__ void acc8(float* a, uint4 w) {
    a[0] += __uint_as_float(w.x << 16);
    a[1] += __uint_as_float(w.x & 0xFFFF0000u);
    a[2] += __uint_as_float(w.y << 16);
    a[3] += __uint_as_float(w.y & 0xFFFF0000u);
    a[4] += __uint_as_float(w.z << 16);
    a[5] += __uint_as_float(w.z & 0xFFFF0000u);
    a[6] += __uint_as_float(w.w << 16);
    a[7] += __uint_as_float(w.w & 0xFFFF0000u);
}

__device__ __forceinline__ void reduce_write(float* a, int node, int q, int sub,
                                             float4* __restrict__ out4) {
    #pragma unroll
    for (int r = 0; r < 8; ++r) {
        a[r] += __shfl_down(a[r], 32);
        a[r] += __shfl_down(a[r], 16);
    }
    if (q == 0) {
        unsigned o = (unsigned)node * 32u + (unsigned)sub * 2u;
        out4[o]     = make_float4(a[0], a[1], a[2], a[3]);
        out4[o + 1] = make_float4(a[4], a[5], a[6], a[7]);
    }
}

// K2: sentinel histogram/scan/compact + clamp-free padded gather.
// 500 blocks x 640 threads; wave w serves nodes w and w+10 sequentially.
__global__ __launch_bounds__(640, 5) void sort_gather_kernel(
    const uint4* __restrict__ xb,            // [XB_U4] bf16 rows + zero row
    const uint4* __restrict__ slots4,        // sentinel cells
    const unsigned* __restrict__ ovfcell,    // [K1_BLOCKS*16]
    float4* __restrict__ out4)               // [NUM_NODES*32]
{
    __shared__ unsigned s_src[MAXB];
    __shared__ int h[NPB];
    __shared__ int off20[NPB];
    __shared__ int cur20[NPB];
    __shared__ int s_ovfany;

    int k = blockIdx.x;
    int t = threadIdx.x;

    if (t < NPB) h[t] = 0;
    if (t == 0) s_ovfany = 0;
    // prefill s_src with the zero row: pads need no separate fill phase,
    // and any guard-clamped write leaves a safe value behind.
    for (int i = t; i < MAXB; i += 640) s_src[i] = ZROW;

    // overflow gate: 256 count words, L2-hot, almost always all zero
    if (t < K1_BLOCKS) {
        unsigned oc = ovfcell[t * 16 + 15];
        if (oc) atomicOr(&s_ovfany, 1);
    }

    // bucket's 256 cells = 1024 uint4, 2 coalesced rounds (issued pre-sync)
    const uint4* sb = slots4 + (unsigned)k * 1024u;
    uint4 w40 = sb[t];
    uint4 w41 = (t < 384) ? sb[t + 640] : make_uint4(INV, INV, INV, INV);
    __syncthreads();

    // histogram: valid iff m-field < NPB (sentinel fails the test)
    {
        unsigned m;
        m = w40.x >> 16; if (m < NPB) atomicAdd(&h[m], 1);
        m = w40.y >> 16; if (m < NPB) atomicAdd(&h[m], 1);
        m = w40.z >> 16; if (m < NPB) atomicAdd(&h[m], 1);
        m = w40.w >> 16; if (m < NPB) atomicAdd(&h[m], 1);
        m = w41.x >> 16; if (m < NPB) atomicAdd(&h[m], 1);
        m = w41.y >> 16; if (m < NPB) atomicAdd(&h[m], 1);
        m = w41.z >> 16; if (m < NPB) atomicAdd(&h[m], 1);
        m = w41.w >> 16; if (m < NPB) atomicAdd(&h[m], 1);
    }
    if (s_ovfany && t < K1_BLOCKS) {                 // never in practice
        int oc = (int)min(ovfcell[t * 16 + 15], 15u);
        for (int i = 0; i < oc; ++i) {
            unsigned e = ovfcell[t * 16 + i];
            if ((int)(e >> 19) == k) atomicAdd(&h[(e >> 14) & 31u], 1);
        }
    }
    __syncthreads();

    // 32-lane scan over PADDED sizes: pe(m) = round4(h)+4 (pad quad covers
    // the unconditional prefetch). off = exclusive scan of pe.
    if (t < 32) {
        int val = (t < NPB) ? (((h[t] + 3) & ~3) + 4) : 0;
        int s = val;
        #pragma unroll
        for (int d = 1; d < 32; d <<= 1) {
            int u = __shfl_up(s, d, 32);
            if (t >= d) s += u;
        }
        if (t < NPB) { off20[t] = s - val; cur20[t] = s - val; }
    }
    __syncthreads();

    // compact valid words into [off, off+h) per node; pads stay ZROW
    {
        unsigned m;
        m = w40.x >> 16; if (m < NPB) { int p = atomicAdd(&cur20[m], 1); if (p < MAXB) s_src[p] = w40.x & 0xFFFFu; }
        m = w40.y >> 16; if (m < NPB) { int p = atomicAdd(&cur20[m], 1); if (p < MAXB) s_src[p] = w40.y & 0xFFFFu; }
        m = w40.z >> 16; if (m < NPB) { int p = atomicAdd(&cur20[m], 1); if (p < MAXB) s_src[p] = w40.z & 0xFFFFu; }
        m = w40.w >> 16; if (m < NPB) { int p = atomicAdd(&cur20[m], 1); if (p < MAXB) s_src[p] = w40.w & 0xFFFFu; }
        m = w41.x >> 16; if (m < NPB) { int p = atomicAdd(&cur20[m], 1); if (p < MAXB) s_src[p] = w41.x & 0xFFFFu; }
        m = w41.y >> 16; if (m < NPB) { int p = atomicAdd(&cur20[m], 1); if (p < MAXB) s_src[p] = w41.y & 0xFFFFu; }
        m = w41.z >> 16; if (m < NPB) { int p = atomicAdd(&cur20[m], 1); if (p < MAXB) s_src[p] = w41.z & 0xFFFFu; }
        m = w41.w >> 16; if (m < NPB) { int p = atomicAdd(&cur20[m], 1); if (p < MAXB) s_src[p] = w41.w & 0xFFFFu; }
    }
    if (s_ovfany && t < K1_BLOCKS) {                 // never in practice
        int oc = (int)min(ovfcell[t * 16 + 15], 15u);
        for (int i = 0; i < oc; ++i) {
            unsigned e = ovfcell[t * 16 + i];
            if ((int)(e >> 19) == k) {
                int p = atomicAdd(&cur20[(e >> 14) & 31u], 1);
                if (p < MAXB) s_src[p] = e & 0x3FFFu;
            }
        }
    }
    __syncthreads();

    int wave = t >> 6;          // 0..9
    int lane = t & 63;
    int q    = lane >> 4;       // which edge of the quad
    int sub  = lane & 15;       // 16 B chunk (8 bf16) within the row

    // node A: mask-free, clamp-free loop (pads are the zero row)
    {
        int m = wave;
        int bA = off20[m];
        int eA = (h[m] + 3) & ~3;
        float a[8] = {0.f, 0.f, 0.f, 0.f, 0.f, 0.f, 0.f, 0.f};
        unsigned s = s_src[bA + q];
        uint4 r = xb[s * 16u + (unsigned)sub];
        for (int j = 0; j < eA; j += 4) {
            unsigned s2 = s_src[bA + j + 4 + q];     // pad quad: always safe
            uint4 r2 = xb[s2 * 16u + (unsigned)sub];
            acc8(a, r);
            r = r2;
        }
        reduce_write(a, k * NPB + m, q, sub, out4);
    }
    // node B
    {
        int m = wave + 10;
        int bB = off20[m];
        int eB = (h[m] + 3) & ~3;
        float a[8] = {0.f, 0.f, 0.f, 0.f, 0.f, 0.f, 0.f, 0.f};
        unsigned s = s_src[bB + q];
        uint4 r = xb[s * 16u + (unsigned)sub];
        for (int j = 0; j < eB; j += 4) {
            unsigned s2 = s_src[bB + j + 4 + q];
            uint4 r2 = xb[s2 * 16u + (unsigned)sub];
            acc8(a, r);
            r = r2;
        }
        reduce_write(a, k * NPB + m, q, sub, out4);
    }
}

extern "C" void kernel_launch(void* const* d_in, const int* in_sizes, int n_in,
                              void* d_out, int out_size, void* d_ws, size_t ws_size,
                              hipStream_t stream) {
    const float* x   = (const float*)d_in[0];   // [10000, 128] f32
    const int*   ei  = (const int*)d_in[1];     // [2, 640000] int32
    float*       out = (float*)d_out;           // [10000, 128] f32

    uint4*    xb      = (uint4*)d_ws;                        // 2.56 MB (+zero row)
    unsigned* ovfcell = (unsigned*)(xb + XB_U4);             // 16 KB
    uint4*    slots4  = (uint4*)(ovfcell + K1_BLOCKS * 16);  // 8.19 MB

    // K1: convert x -> bf16 + sentinel-cell scatter + coalesced write-out
    scatter_cvt_kernel<<<K1_BLOCKS, 1024, 0, stream>>>(
        ei, (const float4*)x, xb, ovfcell, slots4);

    // K2: sentinel hist/scan/compact + clamp-free padded gather
    sort_gather_kernel<<<NB, 640, 0, stream>>>(
        xb, (const uint4*)slots4, ovfcell, (float4*)out);
}